// Round 3
// baseline (24981.691 us; speedup 1.0000x reference)
//
#include <hip/hip_runtime.h>
#include <hip/hip_cooperative_groups.h>
#include <stdint.h>

namespace cg = cooperative_groups;

using bf16x8 = __attribute__((ext_vector_type(8))) short;
using f32x4  = __attribute__((ext_vector_type(4))) float;
#define MFMA(a,b,c) __builtin_amdgcn_mfma_f32_16x16x32_bf16((a),(b),(c),0,0,0)

static __device__ __forceinline__ unsigned short f2bf(float x){
  union { float f; uint32_t u; } v; v.f = x;
  return (unsigned short)((v.u + 0x7fffu + ((v.u >> 16) & 1u)) >> 16);
}
static __device__ __forceinline__ float sigm(float x){ return 1.0f/(1.0f+__expf(-x)); }
static __device__ __forceinline__ float tanh_(float x){ return 1.0f - 2.0f/(1.0f+__expf(2.0f*x)); }
// swizzled LDS offsets (T2): break bank conflicts on 1024B/512B-stride rows
static __device__ __forceinline__ int lofs512(int r,int c){ return ((r<<10)+(c<<1)) ^ ((r&7)<<4); }
static __device__ __forceinline__ int lofs256(int r,int c){ return ((r<<9)+(c<<1)) ^ ((r&7)<<4); }

// ---------------- workspace layout (bytes) ----------------
constexpr size_t OFF_WHHN  = 0;          // (2048,512) bf16
constexpr size_t OFF_WHHE  = 2097152;    // (2048,512) bf16
constexpr size_t OFF_WIHN  = 4194304;    // (2048,256) bf16
constexpr size_t OFF_WIHE1 = 5242880;    // Wih_e[:, :256] (2048,256) bf16
constexpr size_t OFF_WIHE2 = 6291456;    // Wih_e[:, 256:] (2048,256) bf16
constexpr size_t OFF_WN1   = 7340032;    // (256,512)
constexpr size_t OFF_WN2   = 7602176;    // (256,256)
constexpr size_t OFF_WE1   = 7733248;    // (512,512)
constexpr size_t OFF_WE2   = 8257536;    // (256,512)
constexpr size_t OFF_WE3   = 8519680;    // (256,256)
constexpr size_t OFF_WSF   = 8650752;    // [Ws1;Wf1] (256,256)
constexpr size_t OFF_WS2   = 8781824;    // (2,128) + pad
constexpr size_t OFF_WF2   = 8782848;    // (128,128)
constexpr size_t OFF_GENE  = 8815616;    // (256,256) bf16
constexpr size_t OFF_HN0   = 8946688;    // node h dbuf (256,512) bf16
constexpr size_t OFF_HN1   = 9208832;
constexpr size_t OFF_BN    = 9470976;    // 2048 f32 fused node bias
constexpr size_t OFF_BE    = 9479168;    // 2048 f32 fused edge bias
constexpr size_t OFF_BSF   = 9487360;    // 256 f32 [bs1;bf1]
constexpr size_t OFF_XWNT  = 9488384;    // (2048,256) f32 transposed
constexpr size_t OFF_XWEGT = 11585536;   // (2048,256) f32 transposed
constexpr size_t OFF_CEN   = 13682688;   // node c (256,512) f32
constexpr size_t OFF_ENTRY = 14206976;   // (62,256,256) bf16
constexpr size_t OFF_HEB0  = 22333440;   // (62,256,512) bf16
constexpr size_t OFF_HEB1  = 38586368;
constexpr size_t OFF_CE    = 54839296;   // (62,256,512) f32
constexpr size_t WS_NEED   = 87345152;

// ---------------- prep ----------------
struct PrepArgs {
  const float *Whh_n,*Whh_e,*Wih_n,*Wih_e,*Wn1,*Wn2,*We1,*We2,*We3,*Ws1,*Ws2,*Wf1,*Wf2,
              *gene,*h0n,*h0e,*bihn,*bhhn,*bihe,*bhhe,*bs1,*bf1;
  unsigned short *oWhhN,*oWhhE,*oWihN,*oWihE1,*oWihE2,*oWn1,*oWn2,*oWe1,*oWe2,*oWe3,
                 *oWsf,*oWs2,*oWf2,*oGene,*oHn0,*oHeb0;
  float *oBn,*oBe,*oBsf;
};

__global__ void k_prep(PrepArgs a){
  const size_t total = 12734976u;
  const size_t stride = (size_t)gridDim.x*blockDim.x;
  for(size_t i=(size_t)blockIdx.x*blockDim.x+threadIdx.x; i<total; i+=stride){
    size_t t=i;
    if(t<1048576){a.oWhhN[t]=f2bf(a.Whh_n[t]);continue;} t-=1048576;
    if(t<1048576){a.oWhhE[t]=f2bf(a.Whh_e[t]);continue;} t-=1048576;
    if(t<524288){a.oWihN[t]=f2bf(a.Wih_n[t]);continue;} t-=524288;
    if(t<524288){a.oWihE1[t]=f2bf(a.Wih_e[(t>>8)*512+(t&255)]);continue;} t-=524288;
    if(t<524288){a.oWihE2[t]=f2bf(a.Wih_e[(t>>8)*512+256+(t&255)]);continue;} t-=524288;
    if(t<131072){a.oWn1[t]=f2bf(a.Wn1[t]);continue;} t-=131072;
    if(t<65536){a.oWn2[t]=f2bf(a.Wn2[t]);continue;} t-=65536;
    if(t<262144){a.oWe1[t]=f2bf(a.We1[t]);continue;} t-=262144;
    if(t<131072){a.oWe2[t]=f2bf(a.We2[t]);continue;} t-=131072;
    if(t<65536){a.oWe3[t]=f2bf(a.We3[t]);continue;} t-=65536;
    if(t<65536){a.oWsf[t]=f2bf(t<32768? a.Ws1[t] : a.Wf1[t-32768]);continue;} t-=65536;
    if(t<256){a.oWs2[t]=f2bf(a.Ws2[t]);continue;} t-=256;
    if(t<16384){a.oWf2[t]=f2bf(a.Wf2[t]);continue;} t-=16384;
    if(t<65536){a.oGene[t]=f2bf(a.gene[t]);continue;} t-=65536;
    if(t<131072){a.oHn0[t]=f2bf(a.h0n[t]);continue;} t-=131072;
    if(t<8126464){a.oHeb0[t]=f2bf(a.h0e[t]);continue;} t-=8126464;
    if(t<2048){a.oBn[t]=a.bihn[t]+a.bhhn[t];continue;} t-=2048;
    if(t<2048){a.oBe[t]=a.bihe[t]+a.bhhe[t];continue;} t-=2048;
    if(t<256){a.oBsf[t]= t<128? a.bs1[t] : a.bf1[t-128];}
  }
}

// out^T[col][row] = A(256,K)@W(N,K)^T + bias  (transposed f32 store for fast acc-init loads)
__global__ __launch_bounds__(256) void k_mlpT(
  const unsigned short* __restrict__ A, const unsigned short* __restrict__ W,
  const float* __restrict__ bias, float* __restrict__ outT, int K)
{
  const int tid=threadIdx.x, lane=tid&63, w=tid>>6, l15=lane&15, l4=lane>>4;
  const int m0=blockIdx.x*64, n0=blockIdx.y*64+w*16;
  const f32x4 fz={0.f,0.f,0.f,0.f};
  f32x4 acc[4]={fz,fz,fz,fz};
  for(int kk=0;kk<(K>>5);++kk){
    int k=kk*32+l4*8;
    bf16x8 b=*(const bf16x8*)(W+(size_t)(n0+l15)*K+k);
    #pragma unroll
    for(int mf=0;mf<4;++mf){
      bf16x8 av=*(const bf16x8*)(A+(size_t)(m0+mf*16+l15)*K+k);
      acc[mf]=MFMA(av,b,acc[mf]);
    }
  }
  const int col=n0+l15; const float bb=bias[col];
  #pragma unroll
  for(int mf=0;mf<4;++mf)
  #pragma unroll
  for(int r=0;r<4;++r)
    outT[(size_t)col*256 + m0+mf*16+l4*4+r] = acc[mf][r]+bb;
}

// ---------------- cooperative mega-kernel ----------------
struct CoopArgs {
  const unsigned short *WhhN,*WhhE,*WihE2,*Wn1,*Wn2,*We1,*We2,*We3,*Wsf,*Ws2,*Wf2;
  const float *xwnT,*xwegT;
  const float *bn1,*bn2,*be1,*be2,*be3,*bsf,*bs2,*bf2;
  const float *c0n,*c0e;
  unsigned short *hn0,*hn1,*entry,*heb0,*heb1;
  float *cen,*ce;
  float *out;
};

// node LSTM gates: 64 tasks of (64 rows x 32 hcols), K=512
static __device__ void node_gates(const CoopArgs& a, int id, int ns,
                                  const unsigned short* hcur, unsigned short* hnxt){
  const int tid=threadIdx.x, lane=tid&63, w=tid>>6, l15=lane&15, l4=lane>>4;
  const int rb=id>>4, hcb=id&15, wm=w>>1, wc=w&1;
  const int r0=rb*64+wm*16, hc0=hcb*32+wc*16;
  f32x4 acc[4];
  #pragma unroll
  for(int g=0;g<4;++g)
    acc[g]=*(const f32x4*)(a.xwnT + (size_t)(g*512+hc0+l15)*256 + r0+l4*4);
  for(int kk=0;kk<16;++kk){
    int k=kk*32+l4*8;
    bf16x8 a0=*(const bf16x8*)(hcur + (size_t)(r0+l15)*512 + k);
    #pragma unroll
    for(int g=0;g<4;++g){
      bf16x8 b=*(const bf16x8*)(a.WhhN + (size_t)(g*512+hc0+l15)*512 + k);
      acc[g]=MFMA(a0,b,acc[g]);
    }
  }
  const float* cesrc = (ns==0)? a.c0n : a.cen;
  #pragma unroll
  for(int r=0;r<4;++r){
    size_t idx=(size_t)(r0+l4*4+r)*512 + hc0+l15;
    float cn = sigm(acc[1][r])*cesrc[idx] + sigm(acc[0][r])*tanh_(acc[2][r]);
    a.cen[idx]=cn;
    hnxt[idx]=f2bf(sigm(acc[3][r])*tanh_(cn));
  }
}

// entry MLP: 4 tasks of 64 rows; T=relu(h@Wn1+bn1) in LDS, entry=T@Wn2+bn2
static __device__ void entry_task(const CoopArgs& a, int id, int ns,
                                  const unsigned short* hnew, char* X){
  const int tid=threadIdx.x, lane=tid&63, w=tid>>6, l15=lane&15, l4=lane>>4;
  const int base=id*64, c0=w*32;
  const f32x4 fz={0.f,0.f,0.f,0.f};
  {
    f32x4 acc[4][2];
    #pragma unroll
    for(int mf=0;mf<4;++mf){acc[mf][0]=fz;acc[mf][1]=fz;}
    for(int kk=0;kk<16;++kk){
      int k=kk*32+l4*8;
      bf16x8 av[4];
      #pragma unroll
      for(int mf=0;mf<4;++mf) av[mf]=*(const bf16x8*)(hnew+(size_t)(base+mf*16+l15)*512+k);
      #pragma unroll
      for(int nf=0;nf<2;++nf){
        bf16x8 b=*(const bf16x8*)(a.Wn1+(size_t)(c0+nf*16+l15)*512+k);
        #pragma unroll
        for(int mf=0;mf<4;++mf) acc[mf][nf]=MFMA(av[mf],b,acc[mf][nf]);
      }
    }
    #pragma unroll
    for(int mf=0;mf<4;++mf)
    #pragma unroll
    for(int nf=0;nf<2;++nf){
      int col=c0+nf*16+l15; float bb=a.bn1[col];
      #pragma unroll
      for(int r=0;r<4;++r){
        float v=acc[mf][nf][r]+bb;
        *(unsigned short*)(X+lofs256(mf*16+l4*4+r,col))=f2bf(v>0.f?v:0.f);
      }
    }
  }
  __syncthreads();
  {
    f32x4 acc[4][2];
    #pragma unroll
    for(int mf=0;mf<4;++mf){acc[mf][0]=fz;acc[mf][1]=fz;}
    for(int kk=0;kk<8;++kk){
      int k=kk*32+l4*8;
      bf16x8 av[4];
      #pragma unroll
      for(int mf=0;mf<4;++mf) av[mf]=*(const bf16x8*)(X+lofs256(mf*16+l15,k));
      #pragma unroll
      for(int nf=0;nf<2;++nf){
        bf16x8 b=*(const bf16x8*)(a.Wn2+(size_t)(c0+nf*16+l15)*256+k);
        #pragma unroll
        for(int mf=0;mf<4;++mf) acc[mf][nf]=MFMA(av[mf],b,acc[mf][nf]);
      }
    }
    unsigned short* ent=a.entry+(size_t)ns*65536;
    #pragma unroll
    for(int mf=0;mf<4;++mf)
    #pragma unroll
    for(int nf=0;nf<2;++nf){
      int col=c0+nf*16+l15; float bb=a.bn2[col];
      #pragma unroll
      for(int r=0;r<4;++r)
        ent[(size_t)(base+mf*16+l4*4+r)*256+col]=f2bf(acc[mf][nf][r]+bb);
    }
  }
  __syncthreads();
}

// edge gates: task = (chain s, 32 hcols). 256 rows, K=512(he@WhhE)+256(entry@WihE2), C-init=xwegT
static __device__ void edge_gates(const CoopArgs& a, int s, int hcb, int t,
                                  const unsigned short* hecur, unsigned short* henxt){
  const int tid=threadIdx.x, lane=tid&63, w=tid>>6, l15=lane&15, l4=lane>>4;
  const int r0=w*32, hc=hcb*32;
  const unsigned short* A1=hecur+(size_t)s*131072;
  const unsigned short* A2=a.entry+(size_t)s*65536;
  f32x4 acc[2][8];
  #pragma unroll
  for(int mf=0;mf<2;++mf)
  #pragma unroll
  for(int g=0;g<4;++g)
  #pragma unroll
  for(int hf=0;hf<2;++hf)
    acc[mf][g*2+hf]=*(const f32x4*)(a.xwegT + (size_t)(g*512+hc+hf*16+l15)*256 + r0+mf*16+l4*4);
  for(int kk=0;kk<16;++kk){
    int k=kk*32+l4*8;
    bf16x8 a0=*(const bf16x8*)(A1+(size_t)(r0+l15)*512+k);
    bf16x8 a1=*(const bf16x8*)(A1+(size_t)(r0+16+l15)*512+k);
    #pragma unroll
    for(int g=0;g<4;++g)
    #pragma unroll
    for(int hf=0;hf<2;++hf){
      bf16x8 b=*(const bf16x8*)(a.WhhE+(size_t)(g*512+hc+hf*16+l15)*512+k);
      acc[0][g*2+hf]=MFMA(a0,b,acc[0][g*2+hf]);
      acc[1][g*2+hf]=MFMA(a1,b,acc[1][g*2+hf]);
    }
  }
  for(int kk=0;kk<8;++kk){
    int k=kk*32+l4*8;
    bf16x8 a0=*(const bf16x8*)(A2+(size_t)(r0+l15)*256+k);
    bf16x8 a1=*(const bf16x8*)(A2+(size_t)(r0+16+l15)*256+k);
    #pragma unroll
    for(int g=0;g<4;++g)
    #pragma unroll
    for(int hf=0;hf<2;++hf){
      bf16x8 b=*(const bf16x8*)(a.WihE2+(size_t)(g*512+hc+hf*16+l15)*256+k);
      acc[0][g*2+hf]=MFMA(a0,b,acc[0][g*2+hf]);
      acc[1][g*2+hf]=MFMA(a1,b,acc[1][g*2+hf]);
    }
  }
  const float* cesrc=((t==0)? a.c0e : a.ce)+(size_t)s*131072;
  float* cedst=a.ce+(size_t)s*131072;
  unsigned short* ho=henxt+(size_t)s*131072;
  #pragma unroll
  for(int mf=0;mf<2;++mf)
  #pragma unroll
  for(int hf=0;hf<2;++hf)
  #pragma unroll
  for(int r=0;r<4;++r){
    size_t idx=(size_t)(r0+mf*16+l4*4+r)*512 + hc+hf*16+l15;
    float i_=acc[mf][0+hf][r], f_=acc[mf][2+hf][r], g_=acc[mf][4+hf][r], o_=acc[mf][6+hf][r];
    float cn=sigm(f_)*cesrc[idx]+sigm(i_)*tanh_(g_);
    cedst[idx]=cn;
    ho[idx]=f2bf(sigm(o_)*tanh_(cn));
  }
}

// FF head for edge output (s, j): task = 32 rows of chain s, whole chain in LDS
static __device__ void ff_task(const CoopArgs& a, int s, int rb, int j,
                               const unsigned short* hecur, char* X, char* Y){
  const int tid=threadIdx.x, lane=tid&63, w=tid>>6, l15=lane&15, l4=lane>>4;
  const unsigned short* he=hecur+(size_t)s*131072+(size_t)rb*16384;
  const f32x4 fz={0.f,0.f,0.f,0.f};
  const size_t FE=1048576;
  // FF1: t1 = relu(he @ We1^T + be1) -> X (32x512, lofs512)
  {
    const int c0=w*64;
    f32x4 acc[2][4];
    #pragma unroll
    for(int mf=0;mf<2;++mf)
    #pragma unroll
    for(int nf=0;nf<4;++nf) acc[mf][nf]=fz;
    for(int kk=0;kk<16;++kk){
      int k=kk*32+l4*8;
      bf16x8 a0=*(const bf16x8*)(he+(size_t)(l15)*512+k);
      bf16x8 a1=*(const bf16x8*)(he+(size_t)(16+l15)*512+k);
      #pragma unroll
      for(int nf=0;nf<4;++nf){
        bf16x8 b=*(const bf16x8*)(a.We1+(size_t)(c0+nf*16+l15)*512+k);
        acc[0][nf]=MFMA(a0,b,acc[0][nf]); acc[1][nf]=MFMA(a1,b,acc[1][nf]);
      }
    }
    #pragma unroll
    for(int mf=0;mf<2;++mf)
    #pragma unroll
    for(int nf=0;nf<4;++nf){
      int col=c0+nf*16+l15; float bb=a.be1[col];
      #pragma unroll
      for(int r=0;r<4;++r){
        float v=acc[mf][nf][r]+bb;
        *(unsigned short*)(X+lofs512(mf*16+l4*4+r,col))=f2bf(v>0.f?v:0.f);
      }
    }
  }
  __syncthreads();
  // FF2: t2 = relu(t1 @ We2^T + be2) -> Y (32x256, lofs256)
  {
    const int c0=w*32;
    f32x4 acc[2][2]={{fz,fz},{fz,fz}};
    for(int kk=0;kk<16;++kk){
      int k=kk*32+l4*8;
      bf16x8 a0=*(const bf16x8*)(X+lofs512(l15,k));
      bf16x8 a1=*(const bf16x8*)(X+lofs512(16+l15,k));
      #pragma unroll
      for(int nf=0;nf<2;++nf){
        bf16x8 b=*(const bf16x8*)(a.We2+(size_t)(c0+nf*16+l15)*512+k);
        acc[0][nf]=MFMA(a0,b,acc[0][nf]); acc[1][nf]=MFMA(a1,b,acc[1][nf]);
      }
    }
    #pragma unroll
    for(int mf=0;mf<2;++mf)
    #pragma unroll
    for(int nf=0;nf<2;++nf){
      int col=c0+nf*16+l15; float bb=a.be2[col];
      #pragma unroll
      for(int r=0;r<4;++r){
        float v=acc[mf][nf][r]+bb;
        *(unsigned short*)(Y+lofs256(mf*16+l4*4+r,col))=f2bf(v>0.f?v:0.f);
      }
    }
  }
  __syncthreads();
  // FF3: t = t2 @ We3^T + be3 -> X (32x256, lofs256)
  {
    const int c0=w*32;
    f32x4 acc[2][2]={{fz,fz},{fz,fz}};
    for(int kk=0;kk<8;++kk){
      int k=kk*32+l4*8;
      bf16x8 a0=*(const bf16x8*)(Y+lofs256(l15,k));
      bf16x8 a1=*(const bf16x8*)(Y+lofs256(16+l15,k));
      #pragma unroll
      for(int nf=0;nf<2;++nf){
        bf16x8 b=*(const bf16x8*)(a.We3+(size_t)(c0+nf*16+l15)*256+k);
        acc[0][nf]=MFMA(a0,b,acc[0][nf]); acc[1][nf]=MFMA(a1,b,acc[1][nf]);
      }
    }
    #pragma unroll
    for(int mf=0;mf<2;++mf)
    #pragma unroll
    for(int nf=0;nf<2;++nf){
      int col=c0+nf*16+l15; float bb=a.be3[col];
      #pragma unroll
      for(int r=0;r<4;++r)
        *(unsigned short*)(X+lofs256(mf*16+l4*4+r,col))=f2bf(acc[mf][nf][r]+bb);
    }
  }
  __syncthreads();
  // FF4: u = relu(t @ [Ws1;Wf1]^T + bsf) -> Y
  {
    const int c0=w*32;
    f32x4 acc[2][2]={{fz,fz},{fz,fz}};
    for(int kk=0;kk<8;++kk){
      int k=kk*32+l4*8;
      bf16x8 a0=*(const bf16x8*)(X+lofs256(l15,k));
      bf16x8 a1=*(const bf16x8*)(X+lofs256(16+l15,k));
      #pragma unroll
      for(int nf=0;nf<2;++nf){
        bf16x8 b=*(const bf16x8*)(a.Wsf+(size_t)(c0+nf*16+l15)*256+k);
        acc[0][nf]=MFMA(a0,b,acc[0][nf]); acc[1][nf]=MFMA(a1,b,acc[1][nf]);
      }
    }
    #pragma unroll
    for(int mf=0;mf<2;++mf)
    #pragma unroll
    for(int nf=0;nf<2;++nf){
      int col=c0+nf*16+l15; float bb=a.bsf[col];
      #pragma unroll
      for(int r=0;r<4;++r){
        float v=acc[mf][nf][r]+bb;
        *(unsigned short*)(Y+lofs256(mf*16+l4*4+r,col))=f2bf(v>0.f?v:0.f);
      }
    }
  }
  __syncthreads();
  // FF5a: ft = u[:,128:] @ Wf2^T + bf2 -> fe scatter
  {
    f32x4 acc[2]={fz,fz};
    for(int kk=0;kk<4;++kk){
      int k=kk*32+l4*8;
      bf16x8 a0=*(const bf16x8*)(Y+lofs256(l15,128+k));
      bf16x8 a1=*(const bf16x8*)(Y+lofs256(16+l15,128+k));
      bf16x8 b=*(const bf16x8*)(a.Wf2+(size_t)(w*16+l15)*128+k);
      acc[0]=MFMA(a0,b,acc[0]); acc[1]=MFMA(a1,b,acc[1]);
    }
    const int colf=w*16+l15; const float bb=a.bf2[colf];
    #pragma unroll
    for(int mf=0;mf<2;++mf)
    #pragma unroll
    for(int r=0;r<4;++r){
      int g=rb*32+mf*16+l4*4+r;
      size_t o=(colf<64)
        ? FE+(size_t)g*262144+(size_t)(s+2)*4096+(size_t)j*64+colf
        : FE+(size_t)g*262144+(size_t)j*4096+(size_t)(s+2)*64+(colf-64);
      a.out[o]=acc[mf][r]+bb;
    }
  }
  // FF5b: sc = sigmoid(u[:,:128] @ Ws2^T + bs2) -> ex scatter
  if(w==0){
    f32x4 acc[2]={fz,fz};
    const bf16x8 bz={0,0,0,0,0,0,0,0};
    for(int kk=0;kk<4;++kk){
      int k=kk*32+l4*8;
      bf16x8 a0=*(const bf16x8*)(Y+lofs256(l15,k));
      bf16x8 a1=*(const bf16x8*)(Y+lofs256(16+l15,k));
      bf16x8 b=(l15<2)? *(const bf16x8*)(a.Ws2+(size_t)l15*128+k) : bz;
      acc[0]=MFMA(a0,b,acc[0]); acc[1]=MFMA(a1,b,acc[1]);
    }
    if(l15<2){
      const float bb=a.bs2[l15];
      #pragma unroll
      for(int mf=0;mf<2;++mf)
      #pragma unroll
      for(int r=0;r<4;++r){
        int g=rb*32+mf*16+l4*4+r;
        float v=sigm(acc[mf][r]+bb);
        size_t o=(l15==0)
          ? (size_t)g*4096+(size_t)(s+2)*64+j
          : (size_t)g*4096+(size_t)j*64+(s+2);
        a.out[o]=v;
      }
    }
  }
}

__global__ __launch_bounds__(512,4) void k_coop(CoopArgs a){
  cg::grid_group grid = cg::this_grid();
  __shared__ char smem[49152];
  char* X=smem; char* Y=smem+32768;
  // ---- node phase: 62 sequential steps, 2 grid syncs each ----
  for(int ns=0;ns<62;++ns){
    const unsigned short* hcur=(ns&1)? a.hn1 : a.hn0;
    unsigned short* hnxt=(ns&1)? a.hn0 : a.hn1;
    for(int id=blockIdx.x; id<64; id+=gridDim.x) node_gates(a,id,ns,hcur,hnxt);
    grid.sync();
    for(int id=blockIdx.x; id<4; id+=gridDim.x) entry_task(a,id,ns,hnxt,X);
    grid.sync();
  }
  // ---- edge phase: step-synchronized; gates(step t) || FF(step t-1) ----
  for(int t=0;t<=62;++t){
    const unsigned short* hecur=(t&1)? a.heb1 : a.heb0;
    unsigned short* henxt=(t&1)? a.heb0 : a.heb1;
    const int nG=(t<62)? (62-t)*16 : 0;
    const int nF=(t>=1)? (63-t)*8 : 0;
    for(int id=blockIdx.x; id<nG+nF; id+=gridDim.x){
      if(id<nG) edge_gates(a, t+(id>>4), id&15, t, hecur, henxt);
      else { int f=id-nG; ff_task(a, (t-1)+(f>>3), f&7, t-1, hecur, X, Y); }
    }
    grid.sync();
  }
}

// ---------------- launch ----------------
extern "C" void kernel_launch(void* const* d_in, const int* in_sizes, int n_in,
                              void* d_out, int out_size, void* d_ws, size_t ws_size,
                              hipStream_t stream)
{
  (void)in_sizes; (void)n_in;
  if (ws_size < WS_NEED) return;

  const float* gene  = (const float*)d_in[0];
  const float* Wih_n = (const float*)d_in[1];
  const float* Whh_n = (const float*)d_in[2];
  const float* bih_n = (const float*)d_in[3];
  const float* bhh_n = (const float*)d_in[4];
  const float* Wih_e = (const float*)d_in[5];
  const float* Whh_e = (const float*)d_in[6];
  const float* bih_e = (const float*)d_in[7];
  const float* bhh_e = (const float*)d_in[8];
  const float* Wn1   = (const float*)d_in[9];
  const float* bn1   = (const float*)d_in[10];
  const float* Wn2   = (const float*)d_in[11];
  const float* bn2   = (const float*)d_in[12];
  const float* We1   = (const float*)d_in[13];
  const float* be1   = (const float*)d_in[14];
  const float* We2   = (const float*)d_in[15];
  const float* be2   = (const float*)d_in[16];
  const float* We3   = (const float*)d_in[17];
  const float* be3   = (const float*)d_in[18];
  const float* Ws1   = (const float*)d_in[19];
  const float* bs1   = (const float*)d_in[20];
  const float* Ws2   = (const float*)d_in[21];
  const float* bs2   = (const float*)d_in[22];
  const float* Wf1   = (const float*)d_in[23];
  const float* bf1   = (const float*)d_in[24];
  const float* Wf2   = (const float*)d_in[25];
  const float* bf2   = (const float*)d_in[26];
  const float* h0n   = (const float*)d_in[27];
  const float* c0n   = (const float*)d_in[28];
  const float* h0e   = (const float*)d_in[29];
  const float* c0e   = (const float*)d_in[30];

  char* ws=(char*)d_ws;
  auto U16=[&](size_t o){ return (unsigned short*)(ws+o); };
  auto F32=[&](size_t o){ return (float*)(ws+o); };

  hipMemsetAsync(d_out, 0, (size_t)out_size*sizeof(float), stream);

  PrepArgs pa;
  pa.Whh_n=Whh_n; pa.Whh_e=Whh_e; pa.Wih_n=Wih_n; pa.Wih_e=Wih_e;
  pa.Wn1=Wn1; pa.Wn2=Wn2; pa.We1=We1; pa.We2=We2; pa.We3=We3;
  pa.Ws1=Ws1; pa.Ws2=Ws2; pa.Wf1=Wf1; pa.Wf2=Wf2; pa.gene=gene;
  pa.h0n=h0n; pa.h0e=h0e; pa.bihn=bih_n; pa.bhhn=bhh_n; pa.bihe=bih_e;
  pa.bhhe=bhh_e; pa.bs1=bs1; pa.bf1=bf1;
  pa.oWhhN=U16(OFF_WHHN); pa.oWhhE=U16(OFF_WHHE); pa.oWihN=U16(OFF_WIHN);
  pa.oWihE1=U16(OFF_WIHE1); pa.oWihE2=U16(OFF_WIHE2); pa.oWn1=U16(OFF_WN1);
  pa.oWn2=U16(OFF_WN2); pa.oWe1=U16(OFF_WE1); pa.oWe2=U16(OFF_WE2);
  pa.oWe3=U16(OFF_WE3); pa.oWsf=U16(OFF_WSF); pa.oWs2=U16(OFF_WS2);
  pa.oWf2=U16(OFF_WF2); pa.oGene=U16(OFF_GENE); pa.oHn0=U16(OFF_HN0);
  pa.oHeb0=U16(OFF_HEB0);
  pa.oBn=F32(OFF_BN); pa.oBe=F32(OFF_BE); pa.oBsf=F32(OFF_BSF);
  k_prep<<<4096,256,0,stream>>>(pa);

  // loop-invariant pre-activations (transposed f32)
  k_mlpT<<<dim3(4,32),256,0,stream>>>(U16(OFF_GENE), U16(OFF_WIHN), F32(OFF_BN), F32(OFF_XWNT), 256);
  k_mlpT<<<dim3(4,32),256,0,stream>>>(U16(OFF_GENE), U16(OFF_WIHE1), F32(OFF_BE), F32(OFF_XWEGT), 256);

  CoopArgs ca;
  ca.WhhN=U16(OFF_WHHN); ca.WhhE=U16(OFF_WHHE); ca.WihE2=U16(OFF_WIHE2);
  ca.Wn1=U16(OFF_WN1); ca.Wn2=U16(OFF_WN2);
  ca.We1=U16(OFF_WE1); ca.We2=U16(OFF_WE2); ca.We3=U16(OFF_WE3);
  ca.Wsf=U16(OFF_WSF); ca.Ws2=U16(OFF_WS2); ca.Wf2=U16(OFF_WF2);
  ca.xwnT=F32(OFF_XWNT); ca.xwegT=F32(OFF_XWEGT);
  ca.bn1=bn1; ca.bn2=bn2; ca.be1=be1; ca.be2=be2; ca.be3=be3;
  ca.bsf=F32(OFF_BSF); ca.bs2=bs2; ca.bf2=bf2;
  ca.c0n=c0n; ca.c0e=c0e;
  ca.hn0=U16(OFF_HN0); ca.hn1=U16(OFF_HN1); ca.entry=U16(OFF_ENTRY);
  ca.heb0=U16(OFF_HEB0); ca.heb1=U16(OFF_HEB1);
  ca.cen=F32(OFF_CEN); ca.ce=F32(OFF_CE);
  ca.out=(float*)d_out;

  int occ=0;
  hipOccupancyMaxActiveBlocksPerMultiprocessor(&occ, k_coop, 512, 0);
  if(occ<1) occ=1;
  hipDeviceProp_t props;
  hipGetDeviceProperties(&props, 0);
  int ncu = props.multiProcessorCount > 0 ? props.multiProcessorCount : 256;
  dim3 grid((unsigned)(occ*ncu)), block(512);
  void* params[] = { (void*)&ca };
  hipLaunchCooperativeKernel((const void*)k_coop, grid, block, params, 0, stream);
}